// Round 1
// baseline (1160.954 us; speedup 1.0000x reference)
//
#include <hip/hip_runtime.h>
#include <math.h>

#define DEVI static __device__ __forceinline__

namespace {

constexpr float BN_SCALE_C = 0.9999950000374997f; // 1/sqrt(1+1e-5)

DEVI float sigmoidf_(float x){ return 1.0f/(1.0f+expf(-x)); }
DEVI float siluf_(float x){ return x/(1.0f+expf(-x)); }
DEVI float softplusf_(float x){ return fmaxf(x,0.0f) + log1pf(expf(-fabsf(x))); }

__device__ float bred_sum256(float v, float* sh){
  int t=threadIdx.x;
  __syncthreads();
  sh[t]=v; __syncthreads();
  for(int s=128;s>0;s>>=1){ if(t<s) sh[t]+=sh[t+s]; __syncthreads(); }
  return sh[0];
}
__device__ float bred_max256(float v, float* sh){
  int t=threadIdx.x;
  __syncthreads();
  sh[t]=v; __syncthreads();
  for(int s=128;s>0;s>>=1){ if(t<s) sh[t]=fmaxf(sh[t],sh[t+s]); __syncthreads(); }
  return sh[0];
}

// C[M,N] = act(A[M,K] @ (BT ? Bp[N,K]^T : Bp[K,N]) + bias)
// ACT: 0 none, 1 softplus, 2 sigmoid, 3 tanh
template<int ACT, bool BT>
__global__ __launch_bounds__(256) void gemm_k(
    const float* __restrict__ A, const float* __restrict__ Bp,
    const float* __restrict__ bias, float* __restrict__ C,
    int M, int N, int K, int lda,
    long sA, long sB, long sC)
{
  __shared__ float As[16][65];
  __shared__ float Bs[16][65];
  const float* Ab = A + blockIdx.z*sA;
  const float* Bb = Bp + blockIdx.z*sB;
  float* Cb = C + blockIdx.z*sC;
  int m0 = blockIdx.y*64, n0 = blockIdx.x*64;
  int tid = threadIdx.x;
  int ty = tid>>4, tx = tid&15;
  float acc[4][4] = {{0.0f}};
  for (int k0=0;k0<K;k0+=16){
    {
      int row = tid>>2, kk=(tid&3)<<2;
      float4 v = *(const float4*)(Ab + (long)(m0+row)*lda + k0+kk);
      As[kk+0][row]=v.x; As[kk+1][row]=v.y; As[kk+2][row]=v.z; As[kk+3][row]=v.w;
    }
    if (BT){
      int row = tid>>2, kk=(tid&3)<<2;
      float4 v = *(const float4*)(Bb + (long)(n0+row)*K + k0+kk);
      Bs[kk+0][row]=v.x; Bs[kk+1][row]=v.y; Bs[kk+2][row]=v.z; Bs[kk+3][row]=v.w;
    } else {
      int kr = tid>>4, nn=(tid&15)<<2;
      float4 v = *(const float4*)(Bb + (long)(k0+kr)*N + n0+nn);
      Bs[kr][nn+0]=v.x; Bs[kr][nn+1]=v.y; Bs[kr][nn+2]=v.z; Bs[kr][nn+3]=v.w;
    }
    __syncthreads();
    #pragma unroll
    for (int k=0;k<16;++k){
      float a[4],b[4];
      #pragma unroll
      for (int i=0;i<4;++i) a[i]=As[k][(ty<<2)+i];
      #pragma unroll
      for (int j=0;j<4;++j) b[j]=Bs[k][(tx<<2)+j];
      #pragma unroll
      for (int i=0;i<4;++i)
        #pragma unroll
        for (int j=0;j<4;++j) acc[i][j] = fmaf(a[i],b[j],acc[i][j]);
    }
    __syncthreads();
  }
  #pragma unroll
  for (int i=0;i<4;++i){
    int m = m0+(ty<<2)+i;
    #pragma unroll
    for (int j=0;j<4;++j){
      int n = n0+(tx<<2)+j;
      float v = acc[i][j] + (bias?bias[n]:0.0f);
      if (ACT==1) v = softplusf_(v);
      else if (ACT==2) v = sigmoidf_(v);
      else if (ACT==3) v = tanhf(v);
      Cb[(long)m*N+n] = v;
    }
  }
}

// x_f = silu(xi*cfw+cfb);  x_b = silu(flip_L(xi)*cbw+cbb)
__global__ __launch_bounds__(256) void conv_k(const float* __restrict__ xi,
    const float* __restrict__ cfw, const float* __restrict__ cfb,
    const float* __restrict__ cbw, const float* __restrict__ cbb,
    float* __restrict__ xf, float* __restrict__ xb)
{
  int i = blockIdx.x*256 + threadIdx.x;   // B*L*E
  int e = i & 1023;
  int bl = i >> 10;
  int l = bl & 1023, b = bl >> 10;
  xf[i] = siluf_(fmaf(xi[i], cfw[e], cfb[e]));
  int j = (((b<<10) + (1023-l))<<10) + e;
  xb[i] = siluf_(fmaf(xi[j], cbw[e], cbb[e]));
}

// zt[b,s,e] = silu(mean_{j<16} z[b, s*16+j, e])
__global__ __launch_bounds__(256) void zt_k(const float* __restrict__ z, float* __restrict__ zt)
{
  int i = blockIdx.x*256 + threadIdx.x;  // B*S*E = 131072
  int e = i & 1023; int bs = i >> 10; int s = bs & 63; int b = bs >> 6;
  long base = ((long)((b<<10) + (s<<4)))<<10;
  base += e;
  float sm=0.0f;
  #pragma unroll
  for(int j=0;j<16;++j) sm += z[base + ((long)j<<10)];
  zt[i] = siluf_(sm * (1.0f/16.0f));
}

// ---- chunked SSM scan: C=32 chunks of 32 steps; layout [b][c][n][e] ----
__global__ __launch_bounds__(256) void ssm_chunk_k(
    const float* __restrict__ xs, const float* __restrict__ delta,
    const float* __restrict__ dbc, const float* __restrict__ A_log,
    float* __restrict__ pA, float* __restrict__ hend)
{
  __shared__ float sB[32][16];
  int g = blockIdx.x*256 + threadIdx.x;
  int e = g & 1023;
  int bc = g >> 10;
  int c = bc & 31, b = bc >> 5;
  for (int i=threadIdx.x; i<512; i+=256){
    int l=i>>4, n=i&15;
    sB[l][n] = dbc[(((b<<10) + (c<<5) + l)<<6) + 32 + n];
  }
  __syncthreads();
  float An[16];
  #pragma unroll
  for (int n=0;n<16;++n) An[n] = -expf(A_log[(e<<4)+n]);
  float h[16], p[16];
  #pragma unroll
  for (int n=0;n<16;++n){ h[n]=0.0f; p[n]=1.0f; }
  long base = ((long)((b<<10) + (c<<5)))*1024 + e;
  for (int l=0;l<32;++l){
    float dl = delta[base + ((long)l<<10)];
    float xv = xs[base + ((long)l<<10)];
    float dx = dl*xv;
    #pragma unroll
    for (int n=0;n<16;++n){
      float a = expf(dl*An[n]);
      h[n] = fmaf(a, h[n], dx*sB[l][n]);
      p[n] *= a;
    }
  }
  long ob = ((long)((b<<5)+c)<<4)*1024 + e;
  #pragma unroll
  for (int n=0;n<16;++n){ pA[ob + ((long)n<<10)] = p[n]; hend[ob + ((long)n<<10)] = h[n]; }
}

__global__ __launch_bounds__(256) void ssm_carry_k(
    const float* __restrict__ pA, const float* __restrict__ hend, float* __restrict__ Hc)
{
  int g = blockIdx.x*256+threadIdx.x;  // B*E = 2048
  int e = g & 1023, b = g >> 10;
  float H[16];
  #pragma unroll
  for(int n=0;n<16;++n) H[n]=0.0f;
  for (int c=0;c<32;++c){
    long ib = ((long)((b<<5)+c)<<4)*1024 + e;
    #pragma unroll
    for (int n=0;n<16;++n){
      long a = ib + ((long)n<<10);
      Hc[a] = H[n];
      H[n] = fmaf(pA[a], H[n], hend[a]);
    }
  }
}

__global__ __launch_bounds__(256) void ssm_out_k(
    const float* __restrict__ xs, const float* __restrict__ delta,
    const float* __restrict__ dbc, const float* __restrict__ A_log,
    const float* __restrict__ Hc, const float* __restrict__ D,
    float* __restrict__ y)
{
  __shared__ float sB[32][16], sC[32][16];
  int g = blockIdx.x*256+threadIdx.x;
  int e = g & 1023;
  int bc = g >> 10;
  int c = bc & 31, b = bc >> 5;
  for (int i=threadIdx.x;i<512;i+=256){
    int l=i>>4, n=i&15;
    int base = ((b<<10)+(c<<5)+l)<<6;
    sB[l][n] = dbc[base+32+n];
    sC[l][n] = dbc[base+48+n];
  }
  __syncthreads();
  float An[16], h[16];
  long ib = ((long)((b<<5)+c)<<4)*1024 + e;
  #pragma unroll
  for(int n=0;n<16;++n){ An[n] = -expf(A_log[(e<<4)+n]); h[n]=Hc[ib+((long)n<<10)]; }
  float Dv = D[e];
  long base = ((long)((b<<10)+(c<<5)))*1024 + e;
  for (int l=0;l<32;++l){
    float dl = delta[base+((long)l<<10)];
    float xv = xs[base+((long)l<<10)];
    float dx = dl*xv;
    float acc = Dv*xv;
    #pragma unroll
    for(int n=0;n<16;++n){
      float a = expf(dl*An[n]);
      h[n] = fmaf(a,h[n],dx*sB[l][n]);
      acc = fmaf(h[n], sC[l][n], acc);
    }
    y[base+((long)l<<10)] = tanhf(acc);
  }
}

// d[b,l] = || y[b,l,:] - y[b,512,:] ||_2  (width W)
__global__ __launch_bounds__(256) void d2_k(const float* __restrict__ y, float* __restrict__ d, int W)
{
  __shared__ float sh[256];
  int row = blockIdx.x;       // b*1024 + l
  int b = row >> 10;
  const float* rp  = y + (long)row*W;
  const float* ref = y + (long)((b<<10)+512)*W;
  float s=0.0f;
  for(int e=threadIdx.x; e<W; e+=256){ float t=rp[e]-ref[e]; s += t*t; }
  s = bred_sum256(s, sh);
  if (threadIdx.x==0) d[row] = sqrtf(s);
}

// m[b,:] = softmax( gi_norm * (w/wsum) ), w = exp(-0.5 (d/sigma)^2), sigma = mean(d)
__global__ __launch_bounds__(256) void mask_k(const float* __restrict__ d, float* __restrict__ m)
{
  __shared__ float sh[256];
  int b = blockIdx.x, t = threadIdx.x;
  float dl[4]; float s=0.0f;
  #pragma unroll
  for(int i=0;i<4;++i){ dl[i]=d[(b<<10)+t+(i<<8)]; s+=dl[i]; }
  float sigma = bred_sum256(s, sh) * (1.0f/1024.0f);
  float w[4]; s=0.0f;
  float inv_sig = 1.0f/sigma;
  #pragma unroll
  for(int i=0;i<4;++i){ float r=dl[i]*inv_sig; w[i]=expf(-0.5f*r*r); s+=w[i]; }
  float wsum = bred_sum256(s, sh);
  float gi[4]; s=0.0f;
  #pragma unroll
  for(int i=0;i<4;++i){ float q=(float)(t+(i<<8)-512)*(1.0f/256.0f); gi[i]=expf(-0.5f*q*q); s+=gi[i]; }
  float gsum = bred_sum256(s, sh);
  float tv[4]; float mx=-1e30f;
  float sc = 1.0f/(wsum*gsum);
  #pragma unroll
  for(int i=0;i<4;++i){ tv[i]=gi[i]*w[i]*sc; mx=fmaxf(mx,tv[i]); }
  mx = bred_max256(mx, sh);
  float ps=0.0f;
  #pragma unroll
  for(int i=0;i<4;++i){ tv[i]=expf(tv[i]-mx); ps+=tv[i]; }
  ps = bred_sum256(ps, sh);
  float ip = 1.0f/ps;
  #pragma unroll
  for(int i=0;i<4;++i) m[(b<<10)+t+(i<<8)] = tv[i]*ip;
}

// y_cat[b,l,0:E]=y_f*mf[b,l]; y_cat[b,l,E:2E]=y_b*mb[b,1023-l]
__global__ __launch_bounds__(256) void ycat_k(const float* __restrict__ yf, const float* __restrict__ yb,
    const float* __restrict__ mf, const float* __restrict__ mb, float* __restrict__ yc)
{
  int i = blockIdx.x*256 + threadIdx.x;  // B*L*E
  int e = i & 1023; int bl = i >> 10; int l = bl & 1023, b = bl >> 10;
  long r = (long)bl*2048;
  yc[r + e] = yf[i]*mf[bl];
  yc[r + 1024 + e] = yb[i]*mb[(b<<10) + (1023-l)];
}

// in-place: row = y*m;  sc = sigmoid(relu((w0*max+w1*mean+b)*BN));  y = row*sc
__global__ __launch_bounds__(256) void rowscale_k(float* __restrict__ y, const float* __restrict__ m,
    const float* __restrict__ sw, const float* __restrict__ sb)
{
  __shared__ float sh[256];
  int row = blockIdx.x;   // b*L+l
  float mv = m[row];
  float* rp = y + (long)row*1024;
  float v[4]; float mx=-1e30f, sm=0.0f;
  #pragma unroll
  for(int i=0;i<4;++i){ v[i]=rp[threadIdx.x+(i<<8)]*mv; mx=fmaxf(mx,v[i]); sm+=v[i]; }
  float rmax = bred_max256(mx, sh);
  float rsum = bred_sum256(sm, sh);
  float fmap = (sw[0]*rmax + sw[1]*(rsum*(1.0f/1024.0f)) + sb[0])*BN_SCALE_C;
  float sc = sigmoidf_(fmaxf(fmap, 0.0f));
  #pragma unroll
  for(int i=0;i<4;++i) rp[threadIdx.x+(i<<8)] = v[i]*sc;
}

// Aw[b,s,:] = softmax_l( yA[b,:,s] )
__global__ __launch_bounds__(256) void awsm_k(const float* __restrict__ yA, float* __restrict__ Aw)
{
  __shared__ float sh[256];
  int bs = blockIdx.x; int b = bs >> 6, s = bs & 63;
  float v[4]; float mx=-1e30f;
  #pragma unroll
  for(int i=0;i<4;++i){ int l=threadIdx.x+(i<<8); v[i]=yA[(((b<<10)+l)<<6)+s]; mx=fmaxf(mx,v[i]); }
  mx = bred_max256(mx, sh);
  float sm=0.0f;
  #pragma unroll
  for(int i=0;i<4;++i){ v[i]=expf(v[i]-mx); sm+=v[i]; }
  sm = bred_sum256(sm, sh);
  float inv = 1.0f/sm;
  #pragma unroll
  for(int i=0;i<4;++i){ int l=threadIdx.x+(i<<8); Aw[(((b<<6)+s)<<10)+l] = v[i]*inv; }
}

// gz[b,s] = sigmoid(relu((tw0*max_e + tw1*mean_e + tb)*BN)) over zt row
__global__ __launch_bounds__(256) void gz_k(const float* __restrict__ zt, const float* __restrict__ tw,
    const float* __restrict__ tb, float* __restrict__ gz)
{
  __shared__ float sh[256];
  int row = blockIdx.x;  // b*64+s
  const float* rp = zt + (long)row*1024;
  float mx=-1e30f, sm=0.0f;
  #pragma unroll
  for(int i=0;i<4;++i){ float v=rp[threadIdx.x+(i<<8)]; mx=fmaxf(mx,v); sm+=v; }
  mx = bred_max256(mx, sh);
  sm = bred_sum256(sm, sh);
  if (threadIdx.x==0){
    float f = (tw[0]*mx + tw[1]*(sm*(1.0f/1024.0f)) + tb[0])*BN_SCALE_C;
    gz[row] = sigmoidf_(fmaxf(f,0.0f));
  }
}

// O[b,s,e] += zt[b, e%64, s*16+e/64] * gz[b, e%64]
__global__ __launch_bounds__(256) void xjadd_k(float* __restrict__ O, const float* __restrict__ zt,
                                               const float* __restrict__ gz)
{
  int i = blockIdx.x*256+threadIdx.x;  // B*S*E
  int e = i & 1023; int bs = i >> 10; int s = bs & 63; int b = bs >> 6;
  int sz = e & 63; int ez = (s<<4) + (e>>6);
  O[i] += zt[(((b<<6)+sz)<<10) + ez] * gz[(b<<6)+sz];
}

} // namespace

extern "C" void kernel_launch(void* const* d_in, const int* in_sizes, int n_in,
                              void* d_out, int out_size, void* d_ws, size_t ws_size,
                              hipStream_t stream)
{
  (void)in_sizes; (void)n_in; (void)out_size; (void)ws_size;
  const float* x      = (const float*)d_in[0];
  const float* W_in_x = (const float*)d_in[1];
  const float* b_in_x = (const float*)d_in[2];
  const float* W_in_z = (const float*)d_in[3];
  const float* b_in_z = (const float*)d_in[4];
  const float* cfw    = (const float*)d_in[5];
  const float* cfb    = (const float*)d_in[6];
  const float* cbw    = (const float*)d_in[7];
  const float* cbb    = (const float*)d_in[8];
  const float* Wx_f   = (const float*)d_in[9];
  const float* bx_f   = (const float*)d_in[10];
  const float* Wdt_f  = (const float*)d_in[11];
  const float* bdt_f  = (const float*)d_in[12];
  const float* A_log_f= (const float*)d_in[13];
  const float* D_f    = (const float*)d_in[14];
  const float* Wx_b   = (const float*)d_in[15];
  const float* bx_b   = (const float*)d_in[16];
  const float* Wdt_b  = (const float*)d_in[17];
  const float* bdt_b  = (const float*)d_in[18];
  const float* A_log_b= (const float*)d_in[19];
  const float* D_b    = (const float*)d_in[20];
  const float* W_cat  = (const float*)d_in[21];
  const float* b_cat  = (const float*)d_in[22];
  const float* sa_w   = (const float*)d_in[23];
  const float* sa_b   = (const float*)d_in[24];
  const float* wA_f   = (const float*)d_in[25];
  const float* wV_f   = (const float*)d_in[26];
  const float* W_proj = (const float*)d_in[27];
  const float* b_proj = (const float*)d_in[28];
  const float* W_Bi   = (const float*)d_in[29];
  const float* b_Bi   = (const float*)d_in[30];
  const float* tf_w   = (const float*)d_in[31];
  const float* tf_b   = (const float*)d_in[32];
  const float* W_out  = (const float*)d_in[33];
  const float* b_out  = (const float*)d_in[34];
  float* out = (float*)d_out;
  float* ws  = (float*)d_ws;

  const size_t M1 = 1u<<20;
  float* xi   = ws;            // 2M; later reused: pA(1M)+hend(1M), then V(2M)
  float* pA   = ws;
  float* hend = ws + M1;
  float* V    = ws;
  float* z    = ws + 2*M1;     // 2M; reused as delta
  float* delta= z;
  float* xf   = ws + 4*M1;     // 2M \ becomes y_cat (4M)
  float* xb   = ws + 6*M1;     // 2M /
  float* ycat = ws + 4*M1;
  float* yf   = ws + 8*M1;     // 2M; reused as y
  float* ybuf = yf;
  float* yb   = ws + 10*M1;    // 2M
  size_t off  = 12*M1;
  float* dbc  = ws + off; off += 131072;
  float* Hc   = ws + off; off += M1;
  float* ztb  = ws + off; off += 131072;
  float* dvec = ws + off; off += 2048;
  float* mf   = ws + off; off += 2048;
  float* mb   = ws + off; off += 2048;
  float* mv   = ws + off; off += 2048;
  float* gz   = ws + off; off += 256;
  float* yA   = ws + off; off += 131072;
  float* Aw   = ws + off; off += 131072;
  float* u    = ws + off; off += 131072;
  float* Yp   = ws + off; off += 131072;
  float* Bw   = ws + off; off += 8192;
  float* O    = ws + off; off += 131072;

  dim3 blk(256);

  // xi = x@W_in_x^T + b ;  z = x@W_in_z^T + b    (M=2048,N=1024,K=512)
  gemm_k<0,true><<<dim3(16,32,1),blk,0,stream>>>(x, W_in_x, b_in_x, xi, 2048,1024,512,512, 0,0,0);
  gemm_k<0,true><<<dim3(16,32,1),blk,0,stream>>>(x, W_in_z, b_in_z, z, 2048,1024,512,512, 0,0,0);
  conv_k<<<8192,blk,0,stream>>>(xi, cfw,cfb,cbw,cbb, xf, xb);
  zt_k<<<512,blk,0,stream>>>(z, ztb);

  // forward SSM
  gemm_k<0,true><<<dim3(1,32,1),blk,0,stream>>>(xf, Wx_f, bx_f, dbc, 2048,64,1024,1024, 0,0,0);
  gemm_k<1,true><<<dim3(16,32,1),blk,0,stream>>>(dbc, Wdt_f, bdt_f, delta, 2048,1024,32,64, 0,0,0);
  ssm_chunk_k<<<256,blk,0,stream>>>(xf, delta, dbc, A_log_f, pA, hend);
  ssm_carry_k<<<8,blk,0,stream>>>(pA, hend, Hc);
  ssm_out_k<<<256,blk,0,stream>>>(xf, delta, dbc, A_log_f, Hc, D_f, yf);

  // backward SSM
  gemm_k<0,true><<<dim3(1,32,1),blk,0,stream>>>(xb, Wx_b, bx_b, dbc, 2048,64,1024,1024, 0,0,0);
  gemm_k<1,true><<<dim3(16,32,1),blk,0,stream>>>(dbc, Wdt_b, bdt_b, delta, 2048,1024,32,64, 0,0,0);
  ssm_chunk_k<<<256,blk,0,stream>>>(xb, delta, dbc, A_log_b, pA, hend);
  ssm_carry_k<<<8,blk,0,stream>>>(pA, hend, Hc);
  ssm_out_k<<<256,blk,0,stream>>>(xb, delta, dbc, A_log_b, Hc, D_b, yb);

  // masks
  d2_k<<<2048,blk,0,stream>>>(yf, dvec, 1024);
  mask_k<<<2,blk,0,stream>>>(dvec, mf);
  d2_k<<<2048,blk,0,stream>>>(yb, dvec, 1024);
  mask_k<<<2,blk,0,stream>>>(dvec, mb);
  ycat_k<<<8192,blk,0,stream>>>(yf,yb,mf,mb,ycat);
  d2_k<<<2048,blk,0,stream>>>(ycat, dvec, 2048);
  mask_k<<<2,blk,0,stream>>>(dvec, mv);

  // y = ycat@W_cat^T + b_cat ; scale by m and spatial-attn
  gemm_k<0,true><<<dim3(16,32,1),blk,0,stream>>>(ycat, W_cat, b_cat, ybuf, 2048,1024,2048,2048, 0,0,0);
  rowscale_k<<<2048,blk,0,stream>>>(ybuf, mv, sa_w, sa_b);

  // attention head
  gemm_k<0,true><<<dim3(1,32,1),blk,0,stream>>>(ybuf, wA_f, nullptr, yA, 2048,64,1024,1024, 0,0,0);
  awsm_k<<<128,blk,0,stream>>>(yA, Aw);
  gemm_k<0,false><<<dim3(16,32,1),blk,0,stream>>>(ybuf, wV_f, nullptr, V, 2048,1024,1024,1024, 0,0,0);
  gemm_k<0,false><<<dim3(16,1,2),blk,0,stream>>>(Aw, V, nullptr, u, 64,1024,1024,1024, 65536,1048576,65536);

  // tail
  gemm_k<0,true><<<dim3(1,32,1),blk,0,stream>>>(u, W_proj, b_proj, Yp, 2048,64,64,64, 0,0,0);
  gemm_k<2,true><<<dim3(1,2,1),blk,0,stream>>>(ztb, W_Bi, b_Bi, Bw, 128,64,1024,1024, 0,0,0);
  gemm_k<0,false><<<dim3(16,1,2),blk,0,stream>>>(Bw, Yp, nullptr, O, 64,1024,64,64, 4096,65536,65536);
  gz_k<<<128,blk,0,stream>>>(ztb, tf_w, tf_b, gz);
  xjadd_k<<<512,blk,0,stream>>>(O, ztb, gz);
  gemm_k<3,true><<<dim3(8,2,1),blk,0,stream>>>(O, W_out, b_out, out, 128,512,1024,1024, 0,0,0);
}

// Round 2
// 709.171 us; speedup vs baseline: 1.6371x; 1.6371x over previous
//
#include <hip/hip_runtime.h>
#include <math.h>

#define DEVI static __device__ __forceinline__

namespace {

constexpr float BN_SCALE_C = 0.9999950000374997f; // 1/sqrt(1+1e-5)

typedef __bf16 bf8v __attribute__((ext_vector_type(8)));
typedef float f4v __attribute__((ext_vector_type(4)));

DEVI float sigmoidf_(float x){ return 1.0f/(1.0f+expf(-x)); }
DEVI float siluf_(float x){ return x/(1.0f+expf(-x)); }
DEVI float softplusf_(float x){ return fmaxf(x,0.0f) + log1pf(expf(-fabsf(x))); }

DEVI unsigned short f2bf(float f){
  union{float f; unsigned int u;} v; v.f=f;
  unsigned int r = v.u + 0x7fffu + ((v.u>>16)&1u);
  return (unsigned short)(r>>16);
}
DEVI float bf2f(unsigned short u){
  union{unsigned int u; float f;} v; v.u = ((unsigned int)u)<<16;
  return v.f;
}

__device__ float bred_sum256(float v, float* sh){
  int t=threadIdx.x;
  __syncthreads();
  sh[t]=v; __syncthreads();
  for(int s=128;s>0;s>>=1){ if(t<s) sh[t]+=sh[t+s]; __syncthreads(); }
  return sh[0];
}
__device__ float bred_max256(float v, float* sh){
  int t=threadIdx.x;
  __syncthreads();
  sh[t]=v; __syncthreads();
  for(int s=128;s>0;s>>=1){ if(t<s) sh[t]=fmaxf(sh[t],sh[t+s]); __syncthreads(); }
  return sh[0];
}

// ---------------- bf16 MFMA GEMM ----------------
// C[M,N] = act(A[M,K] @ Bt[N,K]^T + bias), A/Bt bf16 (as ushort), C f32.
// BM=BN=64, BK=128, 256 threads (4 waves 2x2, wave tile 32x32).
// M%64==0, N%64==0, K%128==0 required.
template<int ACT>
__global__ __launch_bounds__(256) void gemm_bf16_k(
    const unsigned short* __restrict__ A, const unsigned short* __restrict__ Bt,
    const float* __restrict__ bias, float* __restrict__ C,
    int M, int N, int K)
{
  __shared__ unsigned short As[64*128];
  __shared__ unsigned short Bs[64*128];
  const int tid = threadIdx.x;
  const int m0 = blockIdx.y<<6, n0 = blockIdx.x<<6;
  const int lane = tid & 63, w = tid >> 6;
  const int wr = w >> 1, wc = w & 1;
  const int l15 = lane & 15, l4 = lane >> 4;
  f4v acc[2][2];
  #pragma unroll
  for (int i=0;i<2;++i)
    #pragma unroll
    for(int j=0;j<2;++j) acc[i][j] = (f4v){0.f,0.f,0.f,0.f};

  for (int k0=0; k0<K; k0+=128){
    uint4 ra[4], rb[4];
    #pragma unroll
    for (int i=0;i<4;++i){
      int t = tid + (i<<8);
      int row = t>>4, c = t&15;
      ra[i] = *(const uint4*)(A + (size_t)(m0+row)*K + k0 + (c<<3));
      rb[i] = *(const uint4*)(Bt + (size_t)(n0+row)*K + k0 + (c<<3));
    }
    __syncthreads();   // prev iteration's ds_reads done before overwrite
    #pragma unroll
    for (int i=0;i<4;++i){
      int t = tid + (i<<8);
      int row = t>>4, c = t&15;
      int cs = c ^ (row&7);      // XOR swizzle: kills 16-way read conflict
      *(uint4*)(As + (row<<7) + (cs<<3)) = ra[i];
      *(uint4*)(Bs + (row<<7) + (cs<<3)) = rb[i];
    }
    __syncthreads();
    #pragma unroll
    for (int kk=0;kk<4;++kk){
      int cbase = (kk<<2) + l4;
      bf8v af[2], bfv[2];
      #pragma unroll
      for (int mi=0;mi<2;++mi){
        int row = (wr<<5) + (mi<<4) + l15;
        af[mi] = *(const bf8v*)(As + (row<<7) + ((cbase^(row&7))<<3));
      }
      #pragma unroll
      for (int ni=0;ni<2;++ni){
        int row = (wc<<5) + (ni<<4) + l15;
        bfv[ni] = *(const bf8v*)(Bs + (row<<7) + ((cbase^(row&7))<<3));
      }
      #pragma unroll
      for (int mi=0;mi<2;++mi)
        #pragma unroll
        for (int ni=0;ni<2;++ni)
          acc[mi][ni] = __builtin_amdgcn_mfma_f32_16x16x32_bf16(af[mi], bfv[ni], acc[mi][ni], 0,0,0);
    }
  }
  #pragma unroll
  for (int mi=0;mi<2;++mi){
    #pragma unroll
    for (int ni=0;ni<2;++ni){
      int col = n0 + (wc<<5) + (ni<<4) + l15;
      float bv = bias ? bias[col] : 0.f;
      #pragma unroll
      for (int r=0;r<4;++r){
        int rowg = m0 + (wr<<5) + (mi<<4) + (l4<<2) + r;
        float v = acc[mi][ni][r] + bv;
        if (ACT==3) v = tanhf(v);
        C[(size_t)rowg*N + col] = v;
      }
    }
  }
}

// ---------------- f32 GEMM (kept for sensitive / small shapes) ----------------
// C[M,N] = act(A[M,K] @ (BT ? Bp[N,K]^T : Bp[K,N]) + bias)
// If Bp2 != nullptr: blockIdx.z==1 uses (Bp2,bias2) instead (dual-direction batching).
template<int ACT, bool BT>
__global__ __launch_bounds__(256) void gemm_k(
    const float* __restrict__ A, const float* __restrict__ Bp,
    const float* __restrict__ bias, float* __restrict__ C,
    int M, int N, int K, int lda,
    long sA, long sB, long sC,
    const float* __restrict__ Bp2, const float* __restrict__ bias2)
{
  __shared__ float As[16][65];
  __shared__ float Bs[16][65];
  const float* Ab = A + blockIdx.z*sA;
  const float* Bb; const float* bi;
  if (Bp2 && blockIdx.z){ Bb = Bp2; bi = bias2; }
  else { Bb = Bp + blockIdx.z*sB; bi = bias; }
  float* Cb = C + blockIdx.z*sC;
  int m0 = blockIdx.y*64, n0 = blockIdx.x*64;
  int tid = threadIdx.x;
  int ty = tid>>4, tx = tid&15;
  float acc[4][4] = {{0.0f}};
  for (int k0=0;k0<K;k0+=16){
    {
      int row = tid>>2, kk=(tid&3)<<2;
      float4 v = *(const float4*)(Ab + (long)(m0+row)*lda + k0+kk);
      As[kk+0][row]=v.x; As[kk+1][row]=v.y; As[kk+2][row]=v.z; As[kk+3][row]=v.w;
    }
    if (BT){
      int row = tid>>2, kk=(tid&3)<<2;
      float4 v = *(const float4*)(Bb + (long)(n0+row)*K + k0+kk);
      Bs[kk+0][row]=v.x; Bs[kk+1][row]=v.y; Bs[kk+2][row]=v.z; Bs[kk+3][row]=v.w;
    } else {
      int kr = tid>>4, nn=(tid&15)<<2;
      float4 v = *(const float4*)(Bb + (long)(k0+kr)*N + n0+nn);
      Bs[kr][nn+0]=v.x; Bs[kr][nn+1]=v.y; Bs[kr][nn+2]=v.z; Bs[kr][nn+3]=v.w;
    }
    __syncthreads();
    #pragma unroll
    for (int k=0;k<16;++k){
      float a[4],b[4];
      #pragma unroll
      for (int i=0;i<4;++i) a[i]=As[k][(ty<<2)+i];
      #pragma unroll
      for (int j=0;j<4;++j) b[j]=Bs[k][(tx<<2)+j];
      #pragma unroll
      for (int i=0;i<4;++i)
        #pragma unroll
        for (int j=0;j<4;++j) acc[i][j] = fmaf(a[i],b[j],acc[i][j]);
    }
    __syncthreads();
  }
  #pragma unroll
  for (int i=0;i<4;++i){
    int m = m0+(ty<<2)+i;
    #pragma unroll
    for (int j=0;j<4;++j){
      int n = n0+(tx<<2)+j;
      float v = acc[i][j] + (bi?bi[n]:0.0f);
      if (ACT==1) v = softplusf_(v);
      else if (ACT==2) v = sigmoidf_(v);
      else if (ACT==3) v = tanhf(v);
      Cb[(long)m*N+n] = v;
    }
  }
}

// ---------------- casts ----------------
// 4 flat f32->bf16 segments in one launch; sizes multiple of 4.
__global__ __launch_bounds__(256) void cast4_k(
    const float* __restrict__ s0, unsigned short* __restrict__ d0, int n0,
    const float* __restrict__ s1, unsigned short* __restrict__ d1, int n1,
    const float* __restrict__ s2, unsigned short* __restrict__ d2, int n2,
    const float* __restrict__ s3, unsigned short* __restrict__ d3, int n3)
{
  int i = (blockIdx.x*256 + threadIdx.x)*4;
  const float* s; unsigned short* d;
  if (i < n0){ s = s0; d = d0; }
  else if ((i -= n0) < n1){ s = s1; d = d1; }
  else if ((i -= n1) < n2){ s = s2; d = d2; }
  else if ((i -= n2) < n3){ s = s3; d = d3; }
  else return;
  float4 v = *(const float4*)(s + i);
  union{ unsigned short u[4]; uint2 p; } o;
  o.u[0]=f2bf(v.x); o.u[1]=f2bf(v.y); o.u[2]=f2bf(v.z); o.u[3]=f2bf(v.w);
  *(uint2*)(d + i) = o.p;
}

// wVT[n][k] = bf16(wV[k][n]), 1024x1024
__global__ __launch_bounds__(256) void castT_k(const float* __restrict__ wV, unsigned short* __restrict__ wVT)
{
  __shared__ float t[32][33];
  int bx = blockIdx.x, by = blockIdx.y;
  int tx = threadIdx.x & 31, ty = threadIdx.x >> 5;
  #pragma unroll
  for (int r=0;r<4;++r){
    int row = by*32 + ty + r*8;
    t[ty + r*8][tx] = wV[(long)row*1024 + bx*32 + tx];
  }
  __syncthreads();
  #pragma unroll
  for (int r=0;r<4;++r){
    int row = bx*32 + ty + r*8;
    wVT[(long)row*1024 + by*32 + tx] = f2bf(t[tx][ty + r*8]);
  }
}

// ---------------- elementwise / reductions ----------------
__global__ __launch_bounds__(256) void conv_k(const float* __restrict__ xi,
    const float* __restrict__ cfw, const float* __restrict__ cfb,
    const float* __restrict__ cbw, const float* __restrict__ cbb,
    float* __restrict__ xf, float* __restrict__ xb)
{
  int i = blockIdx.x*256 + threadIdx.x;
  int e = i & 1023;
  int bl = i >> 10;
  int l = bl & 1023, b = bl >> 10;
  xf[i] = siluf_(fmaf(xi[i], cfw[e], cfb[e]));
  int j = (((b<<10) + (1023-l))<<10) + e;
  xb[i] = siluf_(fmaf(xi[j], cbw[e], cbb[e]));
}

__global__ __launch_bounds__(256) void zt_k(const float* __restrict__ z, float* __restrict__ zt)
{
  int i = blockIdx.x*256 + threadIdx.x;  // B*S*E
  int e = i & 1023; int bs = i >> 10; int s = bs & 63; int b = bs >> 6;
  long base = ((long)((b<<10) + (s<<4)))<<10;
  base += e;
  float sm=0.0f;
  #pragma unroll
  for(int j=0;j<16;++j) sm += z[base + ((long)j<<10)];
  zt[i] = siluf_(sm * (1.0f/16.0f));
}

// ---- chunked SSM scan, batched over direction via blockIdx.y ----
__global__ __launch_bounds__(256) void ssm_chunk_k(
    const float* __restrict__ xs0, const float* __restrict__ dl0,
    const float* __restrict__ dbc0, const float* __restrict__ A_log_f,
    const float* __restrict__ A_log_b,
    float* __restrict__ pA0, float* __restrict__ hend0)
{
  const int dir = blockIdx.y;
  const float* xs   = xs0  + (size_t)dir*2097152;
  const float* delta= dl0  + (size_t)dir*2097152;
  const float* dbc  = dbc0 + (size_t)dir*131072;
  const float* A_log= dir ? A_log_b : A_log_f;
  float* pA   = pA0   + (size_t)dir*1048576;
  float* hend = hend0 + (size_t)dir*1048576;

  __shared__ float sB[32][16];
  int g = blockIdx.x*256 + threadIdx.x;
  int e = g & 1023;
  int bc = g >> 10;
  int c = bc & 31, b = bc >> 5;
  for (int i=threadIdx.x; i<512; i+=256){
    int l=i>>4, n=i&15;
    sB[l][n] = dbc[(((b<<10) + (c<<5) + l)<<6) + 32 + n];
  }
  __syncthreads();
  float An[16];
  #pragma unroll
  for (int n=0;n<16;++n) An[n] = -__expf(A_log[(e<<4)+n]);
  float h[16], p[16];
  #pragma unroll
  for (int n=0;n<16;++n){ h[n]=0.0f; p[n]=1.0f; }
  long base = ((long)((b<<10) + (c<<5)))*1024 + e;
  for (int l=0;l<32;++l){
    float dl = delta[base + ((long)l<<10)];
    float xv = xs[base + ((long)l<<10)];
    float dx = dl*xv;
    #pragma unroll
    for (int n=0;n<16;++n){
      float a = __expf(dl*An[n]);
      h[n] = fmaf(a, h[n], dx*sB[l][n]);
      p[n] *= a;
    }
  }
  long ob = ((long)((b<<5)+c)<<4)*1024 + e;
  #pragma unroll
  for (int n=0;n<16;++n){ pA[ob + ((long)n<<10)] = p[n]; hend[ob + ((long)n<<10)] = h[n]; }
}

// carry: one thread per (dir,b,n,e) = 65536 threads
__global__ __launch_bounds__(256) void ssm_carry_k(
    const float* __restrict__ pA, const float* __restrict__ hend, float* __restrict__ Hc)
{
  int i = blockIdx.x*256 + threadIdx.x;
  int e = i & 1023, n = (i>>10)&15, b = (i>>14)&1, dir = (i>>15)&1;
  const float* pAd = pA   + (size_t)dir*1048576;
  const float* hd  = hend + (size_t)dir*1048576;
  float* Hd        = Hc   + (size_t)dir*1048576;
  float H = 0.f;
  long base = ((long)(b*512 + n))*1024 + e;   // [b][c][n][e], c stride 16384
  for (int c=0;c<32;++c){
    long a = base + (long)c*16384;
    Hd[a] = H;
    H = fmaf(pAd[a], H, hd[a]);
  }
}

__global__ __launch_bounds__(256) void ssm_out_k(
    const float* __restrict__ xs0, const float* __restrict__ dl0,
    const float* __restrict__ dbc0, const float* __restrict__ A_log_f,
    const float* __restrict__ A_log_b, const float* __restrict__ Hc0,
    const float* __restrict__ D_f, const float* __restrict__ D_b,
    float* __restrict__ y0)
{
  const int dir = blockIdx.y;
  const float* xs   = xs0  + (size_t)dir*2097152;
  const float* delta= dl0  + (size_t)dir*2097152;
  const float* dbc  = dbc0 + (size_t)dir*131072;
  const float* A_log= dir ? A_log_b : A_log_f;
  const float* Hc   = Hc0 + (size_t)dir*1048576;
  const float* D    = dir ? D_b : D_f;
  float* y          = y0 + (size_t)dir*2097152;

  __shared__ float sB[32][16], sC[32][16];
  int g = blockIdx.x*256+threadIdx.x;
  int e = g & 1023;
  int bc = g >> 10;
  int c = bc & 31, b = bc >> 5;
  for (int i=threadIdx.x;i<512;i+=256){
    int l=i>>4, n=i&15;
    int base = ((b<<10)+(c<<5)+l)<<6;
    sB[l][n] = dbc[base+32+n];
    sC[l][n] = dbc[base+48+n];
  }
  __syncthreads();
  float An[16], h[16];
  long ib = ((long)((b<<5)+c)<<4)*1024 + e;
  #pragma unroll
  for(int n=0;n<16;++n){ An[n] = -__expf(A_log[(e<<4)+n]); h[n]=Hc[ib+((long)n<<10)]; }
  float Dv = D[e];
  long base = ((long)((b<<10)+(c<<5)))*1024 + e;
  for (int l=0;l<32;++l){
    float dl = delta[base+((long)l<<10)];
    float xv = xs[base+((long)l<<10)];
    float dx = dl*xv;
    float acc = Dv*xv;
    #pragma unroll
    for(int n=0;n<16;++n){
      float a = __expf(dl*An[n]);
      h[n] = fmaf(a,h[n],dx*sB[l][n]);
      acc = fmaf(h[n], sC[l][n], acc);
    }
    y[base+((long)l<<10)] = tanhf(acc);
  }
}

// d[row] = || y[row,:] - y[(row&~1023)+512,:] ||, f32 rows of width 1024
__global__ __launch_bounds__(256) void d2_k(const float* __restrict__ y, float* __restrict__ d)
{
  __shared__ float sh[256];
  int row = blockIdx.x;
  int b = row >> 10;
  const float* rp  = y + (long)row*1024;
  const float* ref = y + (long)((b<<10)+512)*1024;
  float s=0.0f;
  for(int e=threadIdx.x; e<1024; e+=256){ float t=rp[e]-ref[e]; s += t*t; }
  s = bred_sum256(s, sh);
  if (threadIdx.x==0) d[row] = sqrtf(s);
}

// same, bf16 rows of width 2048
__global__ __launch_bounds__(256) void d2bf_k(const unsigned short* __restrict__ y, float* __restrict__ d)
{
  __shared__ float sh[256];
  int row = blockIdx.x;
  int b = row >> 10;
  const unsigned short* rp  = y + (long)row*2048;
  const unsigned short* ref = y + (long)((b<<10)+512)*2048;
  float s=0.0f;
  for(int e=threadIdx.x; e<2048; e+=256){ float t=bf2f(rp[e])-bf2f(ref[e]); s += t*t; }
  s = bred_sum256(s, sh);
  if (threadIdx.x==0) d[row] = sqrtf(s);
}

__global__ __launch_bounds__(256) void mask_k(const float* __restrict__ d, float* __restrict__ m)
{
  __shared__ float sh[256];
  int b = blockIdx.x, t = threadIdx.x;
  float dl[4]; float s=0.0f;
  #pragma unroll
  for(int i=0;i<4;++i){ dl[i]=d[(b<<10)+t+(i<<8)]; s+=dl[i]; }
  float sigma = bred_sum256(s, sh) * (1.0f/1024.0f);
  float w[4]; s=0.0f;
  float inv_sig = 1.0f/sigma;
  #pragma unroll
  for(int i=0;i<4;++i){ float r=dl[i]*inv_sig; w[i]=expf(-0.5f*r*r); s+=w[i]; }
  float wsum = bred_sum256(s, sh);
  float gi[4]; s=0.0f;
  #pragma unroll
  for(int i=0;i<4;++i){ float q=(float)(t+(i<<8)-512)*(1.0f/256.0f); gi[i]=expf(-0.5f*q*q); s+=gi[i]; }
  float gsum = bred_sum256(s, sh);
  float tv[4]; float mx=-1e30f;
  float sc = 1.0f/(wsum*gsum);
  #pragma unroll
  for(int i=0;i<4;++i){ tv[i]=gi[i]*w[i]*sc; mx=fmaxf(mx,tv[i]); }
  mx = bred_max256(mx, sh);
  float ps=0.0f;
  #pragma unroll
  for(int i=0;i<4;++i){ tv[i]=expf(tv[i]-mx); ps+=tv[i]; }
  ps = bred_sum256(ps, sh);
  float ip = 1.0f/ps;
  #pragma unroll
  for(int i=0;i<4;++i) m[(b<<10)+t+(i<<8)] = tv[i]*ip;
}

// y_cat (bf16 out)
__global__ __launch_bounds__(256) void ycat_k(const float* __restrict__ yf, const float* __restrict__ yb,
    const float* __restrict__ mf, const float* __restrict__ mb, unsigned short* __restrict__ yc)
{
  int i = blockIdx.x*256 + threadIdx.x;
  int e = i & 1023; int bl = i >> 10; int l = bl & 1023, b = bl >> 10;
  long r = (long)bl*2048;
  yc[r + e] = f2bf(yf[i]*mf[bl]);
  yc[r + 1024 + e] = f2bf(yb[i]*mb[(b<<10) + (1023-l)]);
}

// reads f32 y, applies mask + spatial gate, writes bf16
__global__ __launch_bounds__(256) void rowscale_k(const float* __restrict__ y, const float* __restrict__ m,
    const float* __restrict__ sw, const float* __restrict__ sb, unsigned short* __restrict__ yo)
{
  __shared__ float sh[256];
  int row = blockIdx.x;
  float mv = m[row];
  const float* rp = y + (long)row*1024;
  float v[4]; float mx=-1e30f, sm=0.0f;
  #pragma unroll
  for(int i=0;i<4;++i){ v[i]=rp[threadIdx.x+(i<<8)]*mv; mx=fmaxf(mx,v[i]); sm+=v[i]; }
  float rmax = bred_max256(mx, sh);
  float rsum = bred_sum256(sm, sh);
  float fmap = (sw[0]*rmax + sw[1]*(rsum*(1.0f/1024.0f)) + sb[0])*BN_SCALE_C;
  float sc = sigmoidf_(fmaxf(fmap, 0.0f));
  #pragma unroll
  for(int i=0;i<4;++i) yo[(long)row*1024 + threadIdx.x+(i<<8)] = f2bf(v[i]*sc);
}

__global__ __launch_bounds__(256) void awsm_k(const float* __restrict__ yA, float* __restrict__ Aw)
{
  __shared__ float sh[256];
  int bs = blockIdx.x; int b = bs >> 6, s = bs & 63;
  float v[4]; float mx=-1e30f;
  #pragma unroll
  for(int i=0;i<4;++i){ int l=threadIdx.x+(i<<8); v[i]=yA[(((b<<10)+l)<<6)+s]; mx=fmaxf(mx,v[i]); }
  mx = bred_max256(mx, sh);
  float sm=0.0f;
  #pragma unroll
  for(int i=0;i<4;++i){ v[i]=expf(v[i]-mx); sm+=v[i]; }
  sm = bred_sum256(sm, sh);
  float inv = 1.0f/sm;
  #pragma unroll
  for(int i=0;i<4;++i){ int l=threadIdx.x+(i<<8); Aw[(((b<<6)+s)<<10)+l] = v[i]*inv; }
}

__global__ __launch_bounds__(256) void gz_k(const float* __restrict__ zt, const float* __restrict__ tw,
    const float* __restrict__ tb, float* __restrict__ gz)
{
  __shared__ float sh[256];
  int row = blockIdx.x;
  const float* rp = zt + (long)row*1024;
  float mx=-1e30f, sm=0.0f;
  #pragma unroll
  for(int i=0;i<4;++i){ float v=rp[threadIdx.x+(i<<8)]; mx=fmaxf(mx,v); sm+=v; }
  mx = bred_max256(mx, sh);
  sm = bred_sum256(sm, sh);
  if (threadIdx.x==0){
    float f = (tw[0]*mx + tw[1]*(sm*(1.0f/1024.0f)) + tb[0])*BN_SCALE_C;
    gz[row] = sigmoidf_(fmaxf(f,0.0f));
  }
}

__global__ __launch_bounds__(256) void xjadd_k(float* __restrict__ O, const float* __restrict__ zt,
                                               const float* __restrict__ gz)
{
  int i = blockIdx.x*256+threadIdx.x;
  int e = i & 1023; int bs = i >> 10; int s = bs & 63; int b = bs >> 6;
  int sz = e & 63; int ez = (s<<4) + (e>>6);
  O[i] += zt[(((b<<6)+sz)<<10) + ez] * gz[(b<<6)+sz];
}

} // namespace

extern "C" void kernel_launch(void* const* d_in, const int* in_sizes, int n_in,
                              void* d_out, int out_size, void* d_ws, size_t ws_size,
                              hipStream_t stream)
{
  (void)in_sizes; (void)n_in; (void)out_size; (void)ws_size;
  const float* x      = (const float*)d_in[0];
  const float* W_in_x = (const float*)d_in[1];
  const float* b_in_x = (const float*)d_in[2];
  const float* W_in_z = (const float*)d_in[3];
  const float* b_in_z = (const float*)d_in[4];
  const float* cfw    = (const float*)d_in[5];
  const float* cfb    = (const float*)d_in[6];
  const float* cbw    = (const float*)d_in[7];
  const float* cbb    = (const float*)d_in[8];
  const float* Wx_f   = (const float*)d_in[9];
  const float* bx_f   = (const float*)d_in[10];
  const float* Wdt_f  = (const float*)d_in[11];
  const float* bdt_f  = (const float*)d_in[12];
  const float* A_log_f= (const float*)d_in[13];
  const float* D_f    = (const float*)d_in[14];
  const float* Wx_b   = (const float*)d_in[15];
  const float* bx_b   = (const float*)d_in[16];
  const float* Wdt_b  = (const float*)d_in[17];
  const float* bdt_b  = (const float*)d_in[18];
  const float* A_log_b= (const float*)d_in[19];
  const float* D_b    = (const float*)d_in[20];
  const float* W_cat  = (const float*)d_in[21];
  const float* b_cat  = (const float*)d_in[22];
  const float* sa_w   = (const float*)d_in[23];
  const float* sa_b   = (const float*)d_in[24];
  const float* wA_f   = (const float*)d_in[25];
  const float* wV_f   = (const float*)d_in[26];
  const float* W_proj = (const float*)d_in[27];
  const float* b_proj = (const float*)d_in[28];
  const float* W_Bi   = (const float*)d_in[29];
  const float* b_Bi   = (const float*)d_in[30];
  const float* tf_w   = (const float*)d_in[31];
  const float* tf_b   = (const float*)d_in[32];
  const float* W_out  = (const float*)d_in[33];
  const float* b_out  = (const float*)d_in[34];
  float* out = (float*)d_out;
  float* ws  = (float*)d_ws;

  const size_t M1 = 1u<<20;
  // region A [0,2M): xi -> pA
  float* xi   = ws;
  float* pA   = ws;
  // region B [2M,4M): z -> hend
  float* z    = ws + 2*M1;
  float* hend = ws + 2*M1;
  // region C [4M,8M): xf,xb -> ycat_bf [4M,6M), ybuf_bf [6M,7M)
  float* xf   = ws + 4*M1;
  float* xb   = ws + 6*M1;
  unsigned short* ycat_bf = (unsigned short*)(ws + 4*M1);
  unsigned short* ybuf_bf = (unsigned short*)(ws + 6*M1);
  // region D [8M,12M): x_bf/Winx_bf (early) -> yf,yb -> ybufF32
  unsigned short* x_bf    = (unsigned short*)(ws + 8*M1);
  unsigned short* Winx_bf = (unsigned short*)(ws + 8*M1 + 524288);
  float* yf   = ws + 8*M1;
  float* yb   = ws + 10*M1;
  float* ybufF= ws + 8*M1;
  // region E [12M,16M): deltaF,deltaB -> V
  float* deltaF = ws + 12*M1;
  float* V      = ws + 12*M1;
  // region F [16M,18M): Hc
  float* Hc   = ws + 16*M1;
  // region G [18M,19.6M): weight casts
  unsigned short* Wcat_bf = (unsigned short*)(ws + 18*M1);
  unsigned short* wVT_bf  = (unsigned short*)(ws + 19*M1);
  unsigned short* wA_bf   = (unsigned short*)(ws + 19*M1 + 524288);
  // region H [20M,20.25M): dbc
  float* dbcF = ws + 20*M1;
  // smalls
  size_t off  = 20*M1 + 262144;
  float* ztb  = ws + off; off += 131072;
  float* dvec = ws + off; off += 4096;
  float* msk  = ws + off; off += 4096;   // [0,2048)=mf, [2048,4096)=mb
  float* mv   = ws + off; off += 2048;
  float* gz   = ws + off; off += 256;
  float* yA   = ws + off; off += 131072;
  float* Aw   = ws + off; off += 131072;
  float* u    = ws + off; off += 131072;
  float* Yp   = ws + off; off += 131072;
  float* Bw   = ws + off; off += 8192;
  float* O    = ws + off; off += 131072;

  dim3 blk(256);

  // casts: x (1M), W_in_x (512K), W_cat (2M), wA (64K) -> bf16
  cast4_k<<<3648,blk,0,stream>>>(x, x_bf, 1048576,
                                 W_in_x, Winx_bf, 524288,
                                 W_cat, Wcat_bf, 2097152,
                                 wA_f, wA_bf, 65536);
  castT_k<<<dim3(32,32),blk,0,stream>>>(wV_f, wVT_bf);

  // xi = bf16gemm(x, W_in_x^T)+b ; z = f32 (sensitive path)
  gemm_bf16_k<0><<<dim3(16,32),blk,0,stream>>>(x_bf, Winx_bf, b_in_x, xi, 2048,1024,512);
  gemm_k<0,true><<<dim3(16,32,1),blk,0,stream>>>(x, W_in_z, b_in_z, z, 2048,1024,512,512, 0,0,0, nullptr,nullptr);
  conv_k<<<8192,blk,0,stream>>>(xi, cfw,cfb,cbw,cbb, xf, xb);
  zt_k<<<512,blk,0,stream>>>(z, ztb);

  // dbc (both dirs), delta (both dirs)
  gemm_k<0,true><<<dim3(1,32,2),blk,0,stream>>>(xf, Wx_f, bx_f, dbcF, 2048,64,1024,1024,
                                                2*M1, 0, 131072, Wx_b, bx_b);
  gemm_k<1,true><<<dim3(16,32,2),blk,0,stream>>>(dbcF, Wdt_f, bdt_f, deltaF, 2048,1024,32,64,
                                                 131072, 0, 2*M1, Wdt_b, bdt_b);
  // scan (both dirs)
  ssm_chunk_k<<<dim3(256,2),blk,0,stream>>>(xf, deltaF, dbcF, A_log_f, A_log_b, pA, hend);
  ssm_carry_k<<<256,blk,0,stream>>>(pA, hend, Hc);
  ssm_out_k<<<dim3(256,2),blk,0,stream>>>(xf, deltaF, dbcF, A_log_f, A_log_b, Hc, D_f, D_b, yf);

  // masks for yf,yb (batched: rows 0..2047 = f, 2048..4095 = b)
  d2_k<<<4096,blk,0,stream>>>(yf, dvec);
  mask_k<<<4,blk,0,stream>>>(dvec, msk);
  ycat_k<<<8192,blk,0,stream>>>(yf, yb, msk, msk+2048, ycat_bf);
  d2bf_k<<<2048,blk,0,stream>>>(ycat_bf, dvec);
  mask_k<<<2,blk,0,stream>>>(dvec, mv);

  // y = ycat@W_cat^T + b_cat (bf16 MFMA), then mask+spatial gate -> bf16
  gemm_bf16_k<0><<<dim3(16,32),blk,0,stream>>>(ycat_bf, Wcat_bf, b_cat, ybufF, 2048,1024,2048);
  rowscale_k<<<2048,blk,0,stream>>>(ybufF, mv, sa_w, sa_b, ybuf_bf);

  // attention head (bf16 MFMA for yA and V)
  gemm_bf16_k<0><<<dim3(1,32),blk,0,stream>>>(ybuf_bf, wA_bf, nullptr, yA, 2048,64,1024);
  awsm_k<<<128,blk,0,stream>>>(yA, Aw);
  gemm_bf16_k<0><<<dim3(16,32),blk,0,stream>>>(ybuf_bf, wVT_bf, nullptr, V, 2048,1024,1024);
  gemm_k<0,false><<<dim3(16,1,2),blk,0,stream>>>(Aw, V, nullptr, u, 64,1024,1024,1024,
                                                 65536,1048576,65536, nullptr,nullptr);

  // tail (f32 — sensitive path)
  gemm_k<0,true><<<dim3(1,32,1),blk,0,stream>>>(u, W_proj, b_proj, Yp, 2048,64,64,64, 0,0,0, nullptr,nullptr);
  gemm_k<2,true><<<dim3(1,2,1),blk,0,stream>>>(ztb, W_Bi, b_Bi, Bw, 128,64,1024,1024, 0,0,0, nullptr,nullptr);
  gemm_k<0,false><<<dim3(16,1,2),blk,0,stream>>>(Bw, Yp, nullptr, O, 64,1024,64,64,
                                                 4096,65536,65536, nullptr,nullptr);
  gz_k<<<128,blk,0,stream>>>(ztb, tf_w, tf_b, gz);
  xjadd_k<<<512,blk,0,stream>>>(O, ztb, gz);
  gemm_k<3,true><<<dim3(8,2,1),blk,0,stream>>>(O, W_out, b_out, out, 128,512,1024,1024, 0,0,0, nullptr,nullptr);
}

// Round 3
// 245.921 us; speedup vs baseline: 4.7209x; 2.8837x over previous
//
#include <hip/hip_runtime.h>
#include <math.h>

#define DEVI static __device__ __forceinline__

namespace {

constexpr float BN_SCALE_C = 0.9999950000374997f; // 1/sqrt(1+1e-5)

typedef __bf16 bf8v __attribute__((ext_vector_type(8)));
typedef float f4v __attribute__((ext_vector_type(4)));

DEVI float sigmoidf_(float x){ return 1.0f/(1.0f+expf(-x)); }
DEVI float siluf_(float x){ return x/(1.0f+expf(-x)); }
DEVI float softplusf_(float x){ return fmaxf(x,0.0f) + log1pf(expf(-fabsf(x))); }

DEVI unsigned short f2bf(float f){
  union{float f; unsigned int u;} v; v.f=f;
  unsigned int r = v.u + 0x7fffu + ((v.u>>16)&1u);
  return (unsigned short)(r>>16);
}
DEVI float bf2f(unsigned short u){
  union{unsigned int u; float f;} v; v.u = ((unsigned int)u)<<16;
  return v.f;
}

__device__ float bred_sum256(float v, float* sh){
  int t=threadIdx.x;
  __syncthreads();
  sh[t]=v; __syncthreads();
  for(int s=128;s>0;s>>=1){ if(t<s) sh[t]+=sh[t+s]; __syncthreads(); }
  return sh[0];
}
__device__ float bred_max256(float v, float* sh){
  int t=threadIdx.x;
  __syncthreads();
  sh[t]=v; __syncthreads();
  for(int s=128;s>0;s>>=1){ if(t<s) sh[t]=fmaxf(sh[t],sh[t+s]); __syncthreads(); }
  return sh[0];
}

// direct global -> LDS (16B per lane, wave-uniform LDS base + lane*16)
DEVI void gld_lds16(const unsigned short* g, unsigned short* l){
  __builtin_amdgcn_global_load_lds(
      (const __attribute__((address_space(1))) unsigned int*)(g),
      (__attribute__((address_space(3))) unsigned int*)(l), 16, 0, 0);
}

// ---------------- bf16 MFMA GEMM core ----------------
// Tile 64x64, BK=128, 256 threads = 4 waves (2x2), wave tile 32x32.
// Ag = A + m0*lda (+k offset), Bg = Bt + n0*ldb (+k offset); both bf16 [rows][K].
// LDS layout: row-major [64][128] with 16B-chunk swizzle cs = c ^ (row&7).
// global_load_lds writes linearly; the global SOURCE is inverse-swizzled so the
// LDS slot cs holds column-chunk c = cs^(row&7); reads apply the same XOR.
DEVI void gemm_core(const unsigned short* __restrict__ Ag,
                    const unsigned short* __restrict__ Bg,
                    size_t lda, size_t ldb, int ksteps,
                    unsigned short* As, unsigned short* Bs, f4v (&acc)[2][2])
{
  const int tid = threadIdx.x;
  const int lane = tid & 63, w = tid >> 6;
  const int wr = w >> 1, wc = w & 1;
  const int l15 = lane & 15, l4 = lane >> 4;
  const int srow = lane >> 4;      // 0..3 within a 4-row group
  const int scs  = lane & 15;      // LDS 16B-slot this lane fills

  for (int ks = 0; ks < ksteps; ++ks){
    const unsigned short* Ak = Ag + (size_t)ks*128;
    const unsigned short* Bk = Bg + (size_t)ks*128;
    __syncthreads();               // prev iter's ds_reads done before overwrite
    #pragma unroll
    for (int i=0;i<4;++i){
      int r0 = (w<<4) + (i<<2);
      int row = r0 + srow;
      int c = scs ^ (row & 7);     // inverse-swizzled source column-chunk
      gld_lds16(Ak + (size_t)row*lda + (c<<3), As + (r0<<7));
      gld_lds16(Bk + (size_t)row*ldb + (c<<3), Bs + (r0<<7));
    }
    asm volatile("s_waitcnt vmcnt(0)" ::: "memory");
    __syncthreads();
    #pragma unroll
    for (int kk=0;kk<4;++kk){
      int cb = (kk<<2) + l4;
      bf8v af[2], bfv[2];
      #pragma unroll
      for (int mi=0;mi<2;++mi){
        int row = (wr<<5)+(mi<<4)+l15;
        af[mi] = *(const bf8v*)(As + (row<<7) + ((cb^(row&7))<<3));
      }
      #pragma unroll
      for (int ni=0;ni<2;++ni){
        int row = (wc<<5)+(ni<<4)+l15;
        bfv[ni] = *(const bf8v*)(Bs + (row<<7) + ((cb^(row&7))<<3));
      }
      #pragma unroll
      for (int mi=0;mi<2;++mi)
        #pragma unroll
        for (int ni=0;ni<2;++ni)
          acc[mi][ni] = __builtin_amdgcn_mfma_f32_16x16x32_bf16(af[mi], bfv[ni], acc[mi][ni], 0,0,0);
    }
  }
}

// Direct: C[M,N] = A[M,K] @ Bt[N,K]^T + bias (f32 out).
// Optional dual: blockIdx.z==1 uses (Bt2,bias2), C += sC.
__global__ __launch_bounds__(256) void gemm_bf16_k(
    const unsigned short* __restrict__ A, const unsigned short* __restrict__ Bt,
    const float* __restrict__ bias, float* __restrict__ C,
    int N, int K,
    const unsigned short* __restrict__ Bt2, const float* __restrict__ bias2, long sC)
{
  __shared__ unsigned short As[8192], Bs[8192];
  if (Bt2 && blockIdx.z){ Bt = Bt2; bias = bias2; C += sC; }
  const int m0 = blockIdx.y<<6, n0 = blockIdx.x<<6;
  f4v acc[2][2] = {};
  gemm_core(A + (size_t)m0*K, Bt + (size_t)n0*K, K, K, K>>7, As, Bs, acc);
  const int lane = threadIdx.x & 63, w = threadIdx.x >> 6;
  const int wr = w>>1, wc = w&1, l15 = lane&15, l4 = lane>>4;
  #pragma unroll
  for (int mi=0;mi<2;++mi)
    #pragma unroll
    for (int ni=0;ni<2;++ni){
      int col = n0 + (wc<<5) + (ni<<4) + l15;
      float bv = bias ? bias[col] : 0.f;
      #pragma unroll
      for (int r=0;r<4;++r){
        int rowg = m0 + (wr<<5) + (mi<<4) + (l4<<2) + r;
        C[(size_t)rowg*N + col] = acc[mi][ni][r] + bv;
      }
    }
}

// Split-K: P[ch][Mtot][N] partial = A[m0.., ch-chunk] @ B^T.
// B base = Bt + (m0>>mshift)*sB  (per-M-tile operand select, batch/dir).
__global__ __launch_bounds__(256) void gemm_bf16_splitk_k(
    const unsigned short* __restrict__ A, const unsigned short* __restrict__ Bt,
    float* __restrict__ P, int N, int K, int KC, int mshift, long sB)
{
  __shared__ unsigned short As[8192], Bs[8192];
  const int m0 = blockIdx.y<<6, n0 = blockIdx.x<<6, ch = blockIdx.z;
  const unsigned short* Bb = Bt + (size_t)(m0>>mshift)*sB;
  f4v acc[2][2] = {};
  gemm_core(A + (size_t)m0*K + (size_t)ch*KC, Bb + (size_t)n0*K + (size_t)ch*KC,
            K, K, KC>>7, As, Bs, acc);
  const size_t Mtot = (size_t)gridDim.y<<6;
  float* Pc = P + (size_t)ch*Mtot*N;
  const int lane = threadIdx.x & 63, w = threadIdx.x >> 6;
  const int wr = w>>1, wc = w&1, l15 = lane&15, l4 = lane>>4;
  #pragma unroll
  for (int mi=0;mi<2;++mi)
    #pragma unroll
    for (int ni=0;ni<2;++ni){
      int col = n0 + (wc<<5) + (ni<<4) + l15;
      #pragma unroll
      for (int r=0;r<4;++r){
        int rowg = m0 + (wr<<5) + (mi<<4) + (l4<<2) + r;
        Pc[(size_t)rowg*N + col] = acc[mi][ni][r];
      }
    }
}

// reduce over chunks + bias + activation. ACT: 0 none, 2 sigmoid, 3 tanh.
// bias row-select: bb = (m >> mshift) ? b1 : b0, col = i & (N-1).
template<int ACT>
__global__ __launch_bounds__(256) void sk_reduce_k(
    const float* __restrict__ P, const float* __restrict__ b0, const float* __restrict__ b1,
    int mshift, int nshift, int MN, int nch, float* __restrict__ out)
{
  int i = blockIdx.x*256 + threadIdx.x;
  if (i >= MN) return;
  float s = 0.f;
  for (int c=0;c<nch;++c) s += P[(size_t)c*MN + i];
  const float* bb = ((i>>nshift)>>mshift) ? b1 : b0;
  if (bb) s += bb[i & ((1<<nshift)-1)];
  if (ACT==2) s = sigmoidf_(s);
  else if (ACT==3) s = tanhf(s);
  out[i] = s;
}

// ---------------- f32 GEMM (small K / remaining shapes) ----------------
template<int ACT, bool BT>
__global__ __launch_bounds__(256) void gemm_k(
    const float* __restrict__ A, const float* __restrict__ Bp,
    const float* __restrict__ bias, float* __restrict__ C,
    int M, int N, int K, int lda,
    long sA, long sB, long sC,
    const float* __restrict__ Bp2, const float* __restrict__ bias2)
{
  __shared__ float As[16][65];
  __shared__ float Bs[16][65];
  const float* Ab = A + blockIdx.z*sA;
  const float* Bb; const float* bi;
  if (Bp2 && blockIdx.z){ Bb = Bp2; bi = bias2; }
  else { Bb = Bp + blockIdx.z*sB; bi = bias; }
  float* Cb = C + blockIdx.z*sC;
  int m0 = blockIdx.y*64, n0 = blockIdx.x*64;
  int tid = threadIdx.x;
  int ty = tid>>4, tx = tid&15;
  float acc[4][4] = {{0.0f}};
  for (int k0=0;k0<K;k0+=16){
    {
      int row = tid>>2, kk=(tid&3)<<2;
      float4 v = *(const float4*)(Ab + (long)(m0+row)*lda + k0+kk);
      As[kk+0][row]=v.x; As[kk+1][row]=v.y; As[kk+2][row]=v.z; As[kk+3][row]=v.w;
    }
    if (BT){
      int row = tid>>2, kk=(tid&3)<<2;
      float4 v = *(const float4*)(Bb + (long)(n0+row)*K + k0+kk);
      Bs[kk+0][row]=v.x; Bs[kk+1][row]=v.y; Bs[kk+2][row]=v.z; Bs[kk+3][row]=v.w;
    } else {
      int kr = tid>>4, nn=(tid&15)<<2;
      float4 v = *(const float4*)(Bb + (long)(k0+kr)*N + n0+nn);
      Bs[kr][nn+0]=v.x; Bs[kr][nn+1]=v.y; Bs[kr][nn+2]=v.z; Bs[kr][nn+3]=v.w;
    }
    __syncthreads();
    #pragma unroll
    for (int k=0;k<16;++k){
      float a[4],b[4];
      #pragma unroll
      for (int i=0;i<4;++i) a[i]=As[k][(ty<<2)+i];
      #pragma unroll
      for (int j=0;j<4;++j) b[j]=Bs[k][(tx<<2)+j];
      #pragma unroll
      for (int i=0;i<4;++i)
        #pragma unroll
        for (int j=0;j<4;++j) acc[i][j] = fmaf(a[i],b[j],acc[i][j]);
    }
    __syncthreads();
  }
  #pragma unroll
  for (int i=0;i<4;++i){
    int m = m0+(ty<<2)+i;
    #pragma unroll
    for (int j=0;j<4;++j){
      int n = n0+(tx<<2)+j;
      float v = acc[i][j] + (bi?bi[n]:0.0f);
      if (ACT==1) v = softplusf_(v);
      else if (ACT==2) v = sigmoidf_(v);
      else if (ACT==3) v = tanhf(v);
      Cb[(long)m*N+n] = v;
    }
  }
}

// ---------------- casts ----------------
__global__ __launch_bounds__(256) void cast4_k(
    const float* __restrict__ s0, unsigned short* __restrict__ d0, int n0,
    const float* __restrict__ s1, unsigned short* __restrict__ d1, int n1,
    const float* __restrict__ s2, unsigned short* __restrict__ d2, int n2,
    const float* __restrict__ s3, unsigned short* __restrict__ d3, int n3)
{
  int i = (blockIdx.x*256 + threadIdx.x)*4;
  const float* s; unsigned short* d;
  if (i < n0){ s = s0; d = d0; }
  else if ((i -= n0) < n1){ s = s1; d = d1; }
  else if ((i -= n1) < n2){ s = s2; d = d2; }
  else if ((i -= n2) < n3){ s = s3; d = d3; }
  else return;
  float4 v = *(const float4*)(s + i);
  union{ unsigned short u[4]; uint2 p; } o;
  o.u[0]=f2bf(v.x); o.u[1]=f2bf(v.y); o.u[2]=f2bf(v.z); o.u[3]=f2bf(v.w);
  *(uint2*)(d + i) = o.p;
}

// dst[z][n][k] = bf16(src[z][k][n]), 1024x1024 per z
__global__ __launch_bounds__(256) void castT_k(const float* __restrict__ src, unsigned short* __restrict__ dst)
{
  __shared__ float t[32][33];
  size_t bo = (size_t)blockIdx.z << 20;
  int bx = blockIdx.x, by = blockIdx.y;
  int tx = threadIdx.x & 31, ty = threadIdx.x >> 5;
  #pragma unroll
  for (int r=0;r<4;++r){
    int row = by*32 + ty + r*8;
    t[ty + r*8][tx] = src[bo + (long)row*1024 + bx*32 + tx];
  }
  __syncthreads();
  #pragma unroll
  for (int r=0;r<4;++r){
    int row = bx*32 + ty + r*8;
    dst[bo + (long)row*1024 + by*32 + tx] = f2bf(t[tx][ty + r*8]);
  }
}

// ---------------- elementwise / reductions ----------------
__global__ __launch_bounds__(256) void conv_k(const float* __restrict__ xi,
    const float* __restrict__ cfw, const float* __restrict__ cfb,
    const float* __restrict__ cbw, const float* __restrict__ cbb,
    float* __restrict__ xf, float* __restrict__ xb, unsigned short* __restrict__ xfb_bf)
{
  int i = blockIdx.x*256 + threadIdx.x;
  int e = i & 1023;
  int bl = i >> 10;
  int l = bl & 1023, b = bl >> 10;
  float vf = siluf_(fmaf(xi[i], cfw[e], cfb[e]));
  xf[i] = vf; xfb_bf[i] = f2bf(vf);
  int j = (((b<<10) + (1023-l))<<10) + e;
  float vb = siluf_(fmaf(xi[j], cbw[e], cbb[e]));
  xb[i] = vb; xfb_bf[2097152 + i] = f2bf(vb);
}

__global__ __launch_bounds__(256) void zt_k(const float* __restrict__ z, float* __restrict__ zt,
                                            unsigned short* __restrict__ zt_bf)
{
  int i = blockIdx.x*256 + threadIdx.x;  // B*S*E
  int e = i & 1023; int bs = i >> 10; int s = bs & 63; int b = bs >> 6;
  long base = ((long)((b<<10) + (s<<4)))<<10;
  base += e;
  float sm=0.0f;
  #pragma unroll
  for(int j=0;j<16;++j) sm += z[base + ((long)j<<10)];
  float v = siluf_(sm * (1.0f/16.0f));
  zt[i] = v; zt_bf[i] = f2bf(v);
}

// ---- chunked SSM scan, batched over direction via blockIdx.y ----
__global__ __launch_bounds__(256) void ssm_chunk_k(
    const float* __restrict__ xs0, const float* __restrict__ dl0,
    const float* __restrict__ dbc0, const float* __restrict__ A_log_f,
    const float* __restrict__ A_log_b,
    float* __restrict__ pA0, float* __restrict__ hend0)
{
  const int dir = blockIdx.y;
  const float* xs   = xs0  + (size_t)dir*2097152;
  const float* delta= dl0  + (size_t)dir*2097152;
  const float* dbc  = dbc0 + (size_t)dir*131072;
  const float* A_log= dir ? A_log_b : A_log_f;
  float* pA   = pA0   + (size_t)dir*1048576;
  float* hend = hend0 + (size_t)dir*1048576;

  __shared__ float sB[32][16];
  int g = blockIdx.x*256 + threadIdx.x;
  int e = g & 1023;
  int bc = g >> 10;
  int c = bc & 31, b = bc >> 5;
  for (int i=threadIdx.x; i<512; i+=256){
    int l=i>>4, n=i&15;
    sB[l][n] = dbc[(((b<<10) + (c<<5) + l)<<6) + 32 + n];
  }
  __syncthreads();
  float An[16];
  #pragma unroll
  for (int n=0;n<16;++n) An[n] = -__expf(A_log[(e<<4)+n]);
  float h[16], p[16];
  #pragma unroll
  for (int n=0;n<16;++n){ h[n]=0.0f; p[n]=1.0f; }
  long base = ((long)((b<<10) + (c<<5)))*1024 + e;
  for (int l=0;l<32;++l){
    float dl = delta[base + ((long)l<<10)];
    float xv = xs[base + ((long)l<<10)];
    float dx = dl*xv;
    #pragma unroll
    for (int n=0;n<16;++n){
      float a = __expf(dl*An[n]);
      h[n] = fmaf(a, h[n], dx*sB[l][n]);
      p[n] *= a;
    }
  }
  long ob = ((long)((b<<5)+c)<<4)*1024 + e;
  #pragma unroll
  for (int n=0;n<16;++n){ pA[ob + ((long)n<<10)] = p[n]; hend[ob + ((long)n<<10)] = h[n]; }
}

__global__ __launch_bounds__(256) void ssm_carry_k(
    const float* __restrict__ pA, const float* __restrict__ hend, float* __restrict__ Hc)
{
  int i = blockIdx.x*256 + threadIdx.x;
  int e = i & 1023, n = (i>>10)&15, b = (i>>14)&1, dir = (i>>15)&1;
  const float* pAd = pA   + (size_t)dir*1048576;
  const float* hd  = hend + (size_t)dir*1048576;
  float* Hd        = Hc   + (size_t)dir*1048576;
  float H = 0.f;
  long base = ((long)(b*512 + n))*1024 + e;
  for (int c=0;c<32;++c){
    long a = base + (long)c*16384;
    Hd[a] = H;
    H = fmaf(pAd[a], H, hd[a]);
  }
}

__global__ __launch_bounds__(256) void ssm_out_k(
    const float* __restrict__ xs0, const float* __restrict__ dl0,
    const float* __restrict__ dbc0, const float* __restrict__ A_log_f,
    const float* __restrict__ A_log_b, const float* __restrict__ Hc0,
    const float* __restrict__ D_f, const float* __restrict__ D_b,
    float* __restrict__ y0)
{
  const int dir = blockIdx.y;
  const float* xs   = xs0  + (size_t)dir*2097152;
  const float* delta= dl0  + (size_t)dir*2097152;
  const float* dbc  = dbc0 + (size_t)dir*131072;
  const float* A_log= dir ? A_log_b : A_log_f;
  const float* Hc   = Hc0 + (size_t)dir*1048576;
  const float* D    = dir ? D_b : D_f;
  float* y          = y0 + (size_t)dir*2097152;

  __shared__ float sB[32][16], sC[32][16];
  int g = blockIdx.x*256+threadIdx.x;
  int e = g & 1023;
  int bc = g >> 10;
  int c = bc & 31, b = bc >> 5;
  for (int i=threadIdx.x;i<512;i+=256){
    int l=i>>4, n=i&15;
    int base = ((b<<10)+(c<<5)+l)<<6;
    sB[l][n] = dbc[base+32+n];
    sC[l][n] = dbc[base+48+n];
  }
  __syncthreads();
  float An[16], h[16];
  long ib = ((long)((b<<5)+c)<<4)*1024 + e;
  #pragma unroll
  for(int n=0;n<16;++n){ An[n] = -__expf(A_log[(e<<4)+n]); h[n]=Hc[ib+((long)n<<10)]; }
  float Dv = D[e];
  long base = ((long)((b<<10)+(c<<5)))*1024 + e;
  for (int l=0;l<32;++l){
    float dl = delta[base+((long)l<<10)];
    float xv = xs[base+((long)l<<10)];
    float dx = dl*xv;
    float acc = Dv*xv;
    #pragma unroll
    for(int n=0;n<16;++n){
      float a = __expf(dl*An[n]);
      h[n] = fmaf(a,h[n],dx*sB[l][n]);
      acc = fmaf(h[n], sC[l][n], acc);
    }
    y[base+((long)l<<10)] = tanhf(acc);
  }
}

__global__ __launch_bounds__(256) void d2_k(const float* __restrict__ y, float* __restrict__ d)
{
  __shared__ float sh[256];
  int row = blockIdx.x;
  int b = row >> 10;
  const float* rp  = y + (long)row*1024;
  const float* ref = y + (long)((b<<10)+512)*1024;
  float s=0.0f;
  for(int e=threadIdx.x; e<1024; e+=256){ float t=rp[e]-ref[e]; s += t*t; }
  s = bred_sum256(s, sh);
  if (threadIdx.x==0) d[row] = sqrtf(s);
}

__global__ __launch_bounds__(256) void d2bf_k(const unsigned short* __restrict__ y, float* __restrict__ d)
{
  __shared__ float sh[256];
  int row = blockIdx.x;
  int b = row >> 10;
  const unsigned short* rp  = y + (long)row*2048;
  const unsigned short* ref = y + (long)((b<<10)+512)*2048;
  float s=0.0f;
  for(int e=threadIdx.x; e<2048; e+=256){ float t=bf2f(rp[e])-bf2f(ref[e]); s += t*t; }
  s = bred_sum256(s, sh);
  if (threadIdx.x==0) d[row] = sqrtf(s);
}

__global__ __launch_bounds__(256) void mask_k(const float* __restrict__ d, float* __restrict__ m)
{
  __shared__ float sh[256];
  int b = blockIdx.x, t = threadIdx.x;
  float dl[4]; float s=0.0f;
  #pragma unroll
  for(int i=0;i<4;++i){ dl[i]=d[(b<<10)+t+(i<<8)]; s+=dl[i]; }
  float sigma = bred_sum256(s, sh) * (1.0f/1024.0f);
  float w[4]; s=0.0f;
  float inv_sig = 1.0f/sigma;
  #pragma unroll
  for(int i=0;i<4;++i){ float r=dl[i]*inv_sig; w[i]=expf(-0.5f*r*r); s+=w[i]; }
  float wsum = bred_sum256(s, sh);
  float gi[4]; s=0.0f;
  #pragma unroll
  for(int i=0;i<4;++i){ float q=(float)(t+(i<<8)-512)*(1.0f/256.0f); gi[i]=expf(-0.5f*q*q); s+=gi[i]; }
  float gsum = bred_sum256(s, sh);
  float tv[4]; float mx=-1e30f;
  float sc = 1.0f/(wsum*gsum);
  #pragma unroll
  for(int i=0;i<4;++i){ tv[i]=gi[i]*w[i]*sc; mx=fmaxf(mx,tv[i]); }
  mx = bred_max256(mx, sh);
  float ps=0.0f;
  #pragma unroll
  for(int i=0;i<4;++i){ tv[i]=expf(tv[i]-mx); ps+=tv[i]; }
  ps = bred_sum256(ps, sh);
  float ip = 1.0f/ps;
  #pragma unroll
  for(int i=0;i<4;++i) m[(b<<10)+t+(i<<8)] = tv[i]*ip;
}

__global__ __launch_bounds__(256) void ycat_k(const float* __restrict__ yf, const float* __restrict__ yb,
    const float* __restrict__ mf, const float* __restrict__ mb, unsigned short* __restrict__ yc)
{
  int i = blockIdx.x*256 + threadIdx.x;
  int e = i & 1023; int bl = i >> 10; int l = bl & 1023, b = bl >> 10;
  long r = (long)bl*2048;
  yc[r + e] = f2bf(yf[i]*mf[bl]);
  yc[r + 1024 + e] = f2bf(yb[i]*mb[(b<<10) + (1023-l)]);
}

__global__ __launch_bounds__(256) void rowscale_k(const float* __restrict__ y, const float* __restrict__ m,
    const float* __restrict__ sw, const float* __restrict__ sb, unsigned short* __restrict__ yo)
{
  __shared__ float sh[256];
  int row = blockIdx.x;
  float mv = m[row];
  const float* rp = y + (long)row*1024;
  float v[4]; float mx=-1e30f, sm=0.0f;
  #pragma unroll
  for(int i=0;i<4;++i){ v[i]=rp[threadIdx.x+(i<<8)]*mv; mx=fmaxf(mx,v[i]); sm+=v[i]; }
  float rmax = bred_max256(mx, sh);
  float rsum = bred_sum256(sm, sh);
  float fmap = (sw[0]*rmax + sw[1]*(rsum*(1.0f/1024.0f)) + sb[0])*BN_SCALE_C;
  float sc = sigmoidf_(fmaxf(fmap, 0.0f));
  #pragma unroll
  for(int i=0;i<4;++i) yo[(long)row*1024 + threadIdx.x+(i<<8)] = f2bf(v[i]*sc);
}

// softmax over l of yA[b,l,s]; writes bf16 Aw[b*64+s][l]
__global__ __launch_bounds__(256) void awsm_k(const float* __restrict__ yA, unsigned short* __restrict__ Aw)
{
  __shared__ float sh[256];
  int bs = blockIdx.x; int b = bs >> 6, s = bs & 63;
  float v[4]; float mx=-1e30f;
  #pragma unroll
  for(int i=0;i<4;++i){ int l=threadIdx.x+(i<<8); v[i]=yA[(((b<<10)+l)<<6)+s]; mx=fmaxf(mx,v[i]); }
  mx = bred_max256(mx, sh);
  float sm=0.0f;
  #pragma unroll
  for(int i=0;i<4;++i){ v[i]=expf(v[i]-mx); sm+=v[i]; }
  sm = bred_sum256(sm, sh);
  float inv = 1.0f/sm;
  #pragma unroll
  for(int i=0;i<4;++i){ int l=threadIdx.x+(i<<8); Aw[(((b<<6)+s)<<10)+l] = f2bf(v[i]*inv); }
}

__global__ __launch_bounds__(256) void gz_k(const float* __restrict__ zt, const float* __restrict__ tw,
    const float* __restrict__ tb, float* __restrict__ gz)
{
  __shared__ float sh[256];
  int row = blockIdx.x;
  const float* rp = zt + (long)row*1024;
  float mx=-1e30f, sm=0.0f;
  #pragma unroll
  for(int i=0;i<4;++i){ float v=rp[threadIdx.x+(i<<8)]; mx=fmaxf(mx,v); sm+=v; }
  mx = bred_max256(mx, sh);
  sm = bred_sum256(sm, sh);
  if (threadIdx.x==0){
    float f = (tw[0]*mx + tw[1]*(sm*(1.0f/1024.0f)) + tb[0])*BN_SCALE_C;
    gz[row] = sigmoidf_(fmaxf(f,0.0f));
  }
}

// O_bf[i] = bf16( O[i] + zt[b, e&63, (s<<4)+(e>>6)] * gz[b, e&63] )
__global__ __launch_bounds__(256) void xjadd_k(const float* __restrict__ O, const float* __restrict__ zt,
                                               const float* __restrict__ gz, unsigned short* __restrict__ O_bf)
{
  int i = blockIdx.x*256+threadIdx.x;
  int e = i & 1023; int bs = i >> 10; int s = bs & 63; int b = bs >> 6;
  int sz = e & 63; int ez = (s<<4) + (e>>6);
  float v = O[i] + zt[(((b<<6)+sz)<<10) + ez] * gz[(b<<6)+sz];
  O_bf[i] = f2bf(v);
}

} // namespace

extern "C" void kernel_launch(void* const* d_in, const int* in_sizes, int n_in,
                              void* d_out, int out_size, void* d_ws, size_t ws_size,
                              hipStream_t stream)
{
  (void)in_sizes; (void)n_in; (void)out_size; (void)ws_size;
  const float* x      = (const float*)d_in[0];
  const float* W_in_x = (const float*)d_in[1];
  const float* b_in_x = (const float*)d_in[2];
  const float* W_in_z = (const float*)d_in[3];
  const float* b_in_z = (const float*)d_in[4];
  const float* cfw    = (const float*)d_in[5];
  const float* cfb    = (const float*)d_in[6];
  const float* cbw    = (const float*)d_in[7];
  const float* cbb    = (const float*)d_in[8];
  const float* Wx_f   = (const float*)d_in[9];
  const float* bx_f   = (const float*)d_in[10];
  const float* Wdt_f  = (const float*)d_in[11];
  const float* bdt_f  = (const float*)d_in[12];
  const float* A_log_f= (const float*)d_in[13];
  const float* D_f    = (const float*)d_in[14];
  const float* Wx_b   = (const float*)d_in[15];
  const float* bx_b   = (const float*)d_in[16];
  const float* Wdt_b  = (const float*)d_in[17];
  const float* bdt_b  = (const float*)d_in[18];
  const float* A_log_b= (const float*)d_in[19];
  const float* D_b    = (const float*)d_in[20];
  const float* W_cat  = (const float*)d_in[21];
  const float* b_cat  = (const float*)d_in[22];
  const float* sa_w   = (const float*)d_in[23];
  const float* sa_b   = (const float*)d_in[24];
  const float* wA_f   = (const float*)d_in[25];
  const float* wV_f   = (const float*)d_in[26];
  const float* W_proj = (const float*)d_in[27];
  const float* b_proj = (const float*)d_in[28];
  const float* W_Bi   = (const float*)d_in[29];
  const float* b_Bi   = (const float*)d_in[30];
  const float* tf_w   = (const float*)d_in[31];
  const float* tf_b   = (const float*)d_in[32];
  const float* W_out  = (const float*)d_in[33];
  const float* b_out  = (const float*)d_in[34];
  float* out = (float*)d_out;
  float* ws  = (float*)d_ws;

  const size_t M1 = 1u<<20;
  // [0,2M): xi -> pA -> ycat_bf
  float* xi   = ws;
  float* pA   = ws;
  unsigned short* ycat_bf = (unsigned short*)ws;
  // [2M,4M): z -> hend -> ybufF
  float* z     = ws + 2*M1;
  float* hend  = ws + 2*M1;
  float* ybufF = ws + 2*M1;
  // [4M,6M): xf -> ybuf_bf
  float* xf = ws + 4*M1;
  unsigned short* ybuf_bf = (unsigned short*)(ws + 4*M1);
  // [6M,8M): xb -> V
  float* xb = ws + 6*M1;
  float* V  = ws + 6*M1;
  // [8M,10M): yf -> VT_bf
  float* yf = ws + 8*M1;
  unsigned short* VT_bf = (unsigned short*)(ws + 8*M1);
  // [10M,12M): yb -> P2 (splitk partials for yA/u/Bw/final)
  float* yb = ws + 10*M1;
  float* P2 = ws + 10*M1;
  // [12M,16M): xfxb_bf (until dbc splitk) -> deltaF
  unsigned short* xfxb_bf = (unsigned short*)(ws + 12*M1);
  float* deltaF = ws + 12*M1;
  // [16M,18M): x_bf -> Pd (dbc partials) -> Hc
  unsigned short* x_bf = (unsigned short*)(ws + 16*M1);
  float* Pd = ws + 16*M1;
  float* Hc = ws + 16*M1;
  // [18M,18.25M): dbcF
  float* dbcF = ws + 18*M1;
  // weights
  size_t woff = 18*M1 + 262144;
  unsigned short* Winx_bf = (unsigned short*)(ws + woff); woff += 262144;
  unsigned short* Winz_bf = (unsigned short*)(ws + woff); woff += 262144;
  unsigned short* Wcat_bf = (unsigned short*)(ws + woff); woff += M1;
  unsigned short* wVT_bf  = (unsigned short*)(ws + woff); woff += 524288;
  unsigned short* wA_bf   = (unsigned short*)(ws + woff); woff += 32768;
  unsigned short* Wx_bf   = (unsigned short*)(ws + woff); woff += 65536;   // f then b
  unsigned short* WBi_bf  = (unsigned short*)(ws + woff); woff += 32768;
  unsigned short* Wout_bf = (unsigned short*)(ws + woff); woff += 262144;
  // smalls
  float* ztb  = ws + woff; woff += 131072;
  unsigned short* zt_bf = (unsigned short*)(ws + woff); woff += 65536;
  float* dvec = ws + woff; woff += 4096;
  float* msk  = ws + woff; woff += 4096;
  float* mv   = ws + woff; woff += 2048;
  float* gz   = ws + woff; woff += 256;
  float* yA   = ws + woff; woff += 131072;
  unsigned short* Aw_bf = (unsigned short*)(ws + woff); woff += 65536;
  float* u    = ws + woff; woff += 131072;
  float* Yp   = ws + woff; woff += 131072;
  float* Bw   = ws + woff; woff += 8192;
  float* O    = ws + woff; woff += 131072;
  unsigned short* O_bf = (unsigned short*)(ws + woff); woff += 65536;

  dim3 blk(256);

  // ---- casts ----
  cast4_k<<<4096,blk,0,stream>>>(x, x_bf, 1048576,
                                 W_in_x, Winx_bf, 524288,
                                 W_in_z, Winz_bf, 524288,
                                 W_cat, Wcat_bf, 2097152);
  cast4_k<<<256,blk,0,stream>>>(wA_f, wA_bf, 65536,
                                Wx_f, Wx_bf, 65536,
                                Wx_b, Wx_bf + 65536, 65536,
                                W_Bi, WBi_bf, 65536);
  cast4_k<<<512,blk,0,stream>>>(W_out, Wout_bf, 524288,
                                x, x_bf, 0, x, x_bf, 0, x, x_bf, 0);
  castT_k<<<dim3(32,32,1),blk,0,stream>>>(wV_f, wVT_bf);

  // ---- xi & z (dual-output bf16 MFMA GEMM; z gap sC = 2M floats) ----
  gemm_bf16_k<<<dim3(16,32,2),blk,0,stream>>>(x_bf, Winx_bf, b_in_x, xi, 1024, 512,
                                              Winz_bf, b_in_z, 2*M1);
  conv_k<<<8192,blk,0,stream>>>(xi, cfw,cfb,cbw,cbb, xf, xb, xfxb_bf);
  zt_k<<<512,blk,0,stream>>>(z, ztb, zt_bf);

  // ---- dbc via split-K (both dirs: A=[4096][1024], B select by m>>11) ----
  gemm_bf16_splitk_k<<<dim3(1,64,4),blk,0,stream>>>(xfxb_bf, Wx_bf, Pd, 64, 1024, 256, 11, 65536);
  sk_reduce_k<0><<<1024,blk,0,stream>>>(Pd, bx_f, bx_b, 11, 6, 262144, 4, dbcF);

  // ---- delta (f32, K=32) ----
  gemm_k<1,true><<<dim3(16,32,2),blk,0,stream>>>(dbcF, Wdt_f, bdt_f, deltaF, 2048,1024,32,64,
                                                 131072, 0, 2*M1, Wdt_b, bdt_b);
  // ---- scan ----
  ssm_chunk_k<<<dim3(256,2),blk,0,stream>>>(xf, deltaF, dbcF, A_log_f, A_log_b, pA, hend);
  ssm_carry_k<<<256,blk,0,stream>>>(pA, hend, Hc);
  ssm_out_k<<<dim3(256,2),blk,0,stream>>>(xf, deltaF, dbcF, A_log_f, A_log_b, Hc, D_f, D_b, yf);

  // ---- masks ----
  d2_k<<<4096,blk,0,stream>>>(yf, dvec);
  mask_k<<<4,blk,0,stream>>>(dvec, msk);
  ycat_k<<<8192,blk,0,stream>>>(yf, yb, msk, msk+2048, ycat_bf);
  d2bf_k<<<2048,blk,0,stream>>>(ycat_bf, dvec);
  mask_k<<<2,blk,0,stream>>>(dvec, mv);

  // ---- W_cat GEMM + gates ----
  gemm_bf16_k<<<dim3(16,32,1),blk,0,stream>>>(ycat_bf, Wcat_bf, b_cat, ybufF, 1024, 2048,
                                              nullptr, nullptr, 0);
  rowscale_k<<<2048,blk,0,stream>>>(ybufF, mv, sa_w, sa_b, ybuf_bf);

  // ---- attention head ----
  gemm_bf16_splitk_k<<<dim3(1,32,8),blk,0,stream>>>(ybuf_bf, wA_bf, P2, 64, 1024, 128, 31, 0);
  sk_reduce_k<0><<<512,blk,0,stream>>>(P2, nullptr, nullptr, 0, 6, 131072, 8, yA);
  awsm_k<<<128,blk,0,stream>>>(yA, Aw_bf);
  gemm_bf16_k<<<dim3(16,32,1),blk,0,stream>>>(ybuf_bf, wVT_bf, nullptr, V, 1024, 1024,
                                              nullptr, nullptr, 0);
  castT_k<<<dim3(32,32,2),blk,0,stream>>>(V, VT_bf);   // VT[b][e][l]
  gemm_bf16_splitk_k<<<dim3(16,2,8),blk,0,stream>>>(Aw_bf, VT_bf, P2, 1024, 1024, 128, 6, 1048576);
  sk_reduce_k<0><<<512,blk,0,stream>>>(P2, nullptr, nullptr, 0, 10, 131072, 8, u);

  // ---- tail ----
  gemm_k<0,true><<<dim3(1,32,1),blk,0,stream>>>(u, W_proj, b_proj, Yp, 2048,64,64,64, 0,0,0, nullptr,nullptr);
  gemm_bf16_splitk_k<<<dim3(1,2,8),blk,0,stream>>>(zt_bf, WBi_bf, P2, 64, 1024, 128, 31, 0);
  sk_reduce_k<2><<<32,blk,0,stream>>>(P2, b_Bi, b_Bi, 30, 6, 8192, 8, Bw);
  gemm_k<0,false><<<dim3(16,1,2),blk,0,stream>>>(Bw, Yp, nullptr, O, 64,1024,64,64,
                                                 4096,65536,65536, nullptr,nullptr);
  gz_k<<<128,blk,0,stream>>>(ztb, tf_w, tf_b, gz);
  xjadd_k<<<512,blk,0,stream>>>(O, ztb, gz, O_bf);
  gemm_bf16_splitk_k<<<dim3(8,2,8),blk,0,stream>>>(O_bf, Wout_bf, P2, 512, 1024, 128, 31, 0);
  sk_reduce_k<3><<<256,blk,0,stream>>>(P2, b_out, b_out, 30, 9, 65536, 8, out);
}